// Round 11
// baseline (135.357 us; speedup 1.0000x reference)
//
#include <hip/hip_runtime.h>
#include <hip/hip_fp16.h>

constexpr int Hc = 128, Wc = 128, Cc = 64;
constexpr int Qc = 512 * 512;

constexpr int NBLK = 512;                      // 2/CU needed, >=4/CU capacity: safe
constexpr int PIX_PER_BLK = Hc * Wc / NBLK;    // 32 pixels per block
constexpr int CGRP = 256 / PIX_PER_BLK;        // 8 channel groups
constexpr int CPER = Cc / CGRP;                // 8 channels per group
constexpr unsigned MAGIC = 0x5AC3F00Du;        // != 0xAAAAAAAA poison, != 0

// ---------------------------------------------------------------------------
// Fused LIIF, single dispatch (no cooperative API):
//   phase A: 3x3-conv-folded table S (64->3ch, fp16-packed 8B/px, 128 KB)
//   manual grid barrier: per-block MAGIC flag + agent-scope acquire spin.
//     Reset-free: on replays flags may already be MAGIC -> barrier no-ops,
//     but conv rewrites byte-identical values, so the race is benign.
//   phase B: 2 queries/thread, per-axis factored algebra, 2x2 8B gathers.
// ---------------------------------------------------------------------------
__global__ __launch_bounds__(256, 4) void liif_fused(const float* __restrict__ feat,
                                                     const float* __restrict__ coord,
                                                     const float* __restrict__ cell,
                                                     const float* __restrict__ wgt,
                                                     const float* __restrict__ bias,
                                                     uint2* __restrict__ Sp,
                                                     unsigned* flags,
                                                     float* __restrict__ out) {
    // ---------------- phase A: conv3x3 -> packed S ----------------
    __shared__ float ws[576 * 3];
    for (int i = threadIdx.x; i < 576 * 3; i += 256) ws[i] = wgt[i];

    __shared__ float part[CGRP][PIX_PER_BLK][3];   // [8][32][3]

    int px = threadIdx.x & (PIX_PER_BLK - 1);
    int cg = threadIdx.x >> 5;                     // 0..7
    int pix = blockIdx.x * PIX_PER_BLK + px;
    int y = pix >> 7;
    int x = pix & 127;

    __syncthreads();                               // ws ready

    {
        float a0 = 0.f, a1 = 0.f, a2 = 0.f;
        const int c0 = cg * CPER;
#pragma unroll
        for (int ci = 0; ci < CPER; ++ci) {
            int c = c0 + ci;
            const float* fc = feat + c * Hc * Wc;
            const float* wr = ws + c * 27;
#pragma unroll
            for (int di = 0; di < 3; ++di) {
                int yy = y + di - 1;
                bool yok = (unsigned)yy < (unsigned)Hc;
#pragma unroll
                for (int dj = 0; dj < 3; ++dj) {
                    int xx = x + dj - 1;
                    bool ok = yok && ((unsigned)xx < (unsigned)Wc);
                    float v = ok ? fc[yy * Wc + xx] : 0.f;
                    const float* wk = wr + (di * 3 + dj) * 3;
                    a0 = fmaf(v, wk[0], a0);
                    a1 = fmaf(v, wk[1], a1);
                    a2 = fmaf(v, wk[2], a2);
                }
            }
        }
        part[cg][px][0] = a0;
        part[cg][px][1] = a1;
        part[cg][px][2] = a2;
    }
    __syncthreads();

    // tree reduce over channel groups: 8 -> 4 -> 2 -> 1
#pragma unroll
    for (int step = CGRP / 2; step > 0; step >>= 1) {
        if (cg < step) {
            part[cg][px][0] += part[cg + step][px][0];
            part[cg][px][1] += part[cg + step][px][1];
            part[cg][px][2] += part[cg + step][px][2];
        }
        __syncthreads();
    }

    if (cg == 0) {
        unsigned short u0 = __half_as_ushort(__float2half_rn(part[0][px][0]));
        unsigned short u1 = __half_as_ushort(__float2half_rn(part[0][px][1]));
        unsigned short u2 = __half_as_ushort(__float2half_rn(part[0][px][2]));
        uint2 o;
        o.x = (unsigned)u0 | ((unsigned)u1 << 16);
        o.y = (unsigned)u2;
        Sp[pix] = o;
    }

    // ---- preload phase-B inputs (independent of S; hides under the spin) ----
    int t = blockIdx.x * 256 + threadIdx.x;        // NBLK*256 = Qc/2
    int q0 = t * 2;
    float4 co = *reinterpret_cast<const float4*>(coord + q0 * 2);  // x0,y0,x1,y1
    float4 ce = *reinterpret_cast<const float4*>(cell + q0 * 2);
    float wx0 = wgt[576 * 3 + 0], wx1 = wgt[576 * 3 + 1], wx2 = wgt[576 * 3 + 2];
    float wy0 = wgt[577 * 3 + 0], wy1 = wgt[577 * 3 + 1], wy2 = wgt[577 * 3 + 2];
    float wc0 = wgt[578 * 3 + 0], wc1 = wgt[578 * 3 + 1], wc2 = wgt[578 * 3 + 2];
    float wd0 = wgt[579 * 3 + 0], wd1 = wgt[579 * 3 + 1], wd2 = wgt[579 * 3 + 2];
    float b0 = bias[0], b1 = bias[1], b2 = bias[2];

    // ---------------- manual grid barrier ----------------
    __syncthreads();   // emits s_waitcnt vmcnt(0): this block's Sp stores done
    if (threadIdx.x == 0) {
        __threadfence();                           // device-scope release of S
        __hip_atomic_store(&flags[blockIdx.x], MAGIC,
                           __ATOMIC_RELEASE, __HIP_MEMORY_SCOPE_AGENT);
    }
    {
        const unsigned* fp = flags + threadIdx.x * 2;   // 512 flags / 256 thr
        int ok;
        do {
            unsigned f0 = __hip_atomic_load(fp + 0, __ATOMIC_ACQUIRE,
                                            __HIP_MEMORY_SCOPE_AGENT);
            unsigned f1 = __hip_atomic_load(fp + 1, __ATOMIC_ACQUIRE,
                                            __HIP_MEMORY_SCOPE_AGENT);
            ok = (f0 == MAGIC) && (f1 == MAGIC);
        } while (!__syncthreads_and(ok));
    }
    __threadfence();                               // acquire: invalidate caches

    // ---------------- phase B: 2 queries/thread ----------------
    // double-computed constants cast to fp32 (match numpy float64 scalar math)
    constexpr float SHN = (float)(-1.0 / 128.0 + 1e-6);
    constexpr float SHP = (float)( 1.0 / 128.0 + 1e-6);
    constexpr float CLO = (float)(-1.0 + 1e-6);
    constexpr float CHI = (float)( 1.0 - 1e-6);

    float res[6];
#pragma unroll
    for (int k = 0; k < 2; ++k) {
        float cox = k ? co.z : co.x;
        float coy = k ? co.w : co.y;
        float rcx = (k ? ce.z : ce.x) * 128.0f;
        float rcy = (k ? ce.w : ce.y) * 128.0f;

        // ---- per-axis index + rel algebra (shifts are exactly +-0.5 px) ----
        float cxm = fminf(fmaxf(cox + SHN, CLO), CHI);
        float cxp = fminf(fmaxf(cox + SHP, CLO), CHI);
        int ihm = min(max((int)floorf((cxm + 1.0f) * 64.0f), 0), 127);
        int ihp = min(max((int)floorf((cxp + 1.0f) * 64.0f), 0), 127);
        float relxm = (cox - (-1.0f + (float)(2 * ihm + 1) * (1.0f / 128.0f))) * 128.0f;
        float relxp = (cox - (-1.0f + (float)(2 * ihp + 1) * (1.0f / 128.0f))) * 128.0f;

        float cym = fminf(fmaxf(coy + SHN, CLO), CHI);
        float cyp = fminf(fmaxf(coy + SHP, CLO), CHI);
        int iwm = min(max((int)floorf((cym + 1.0f) * 64.0f), 0), 127);
        int iwp = min(max((int)floorf((cyp + 1.0f) * 64.0f), 0), 127);
        float relym = (coy - (-1.0f + (float)(2 * iwm + 1) * (1.0f / 128.0f))) * 128.0f;
        float relyp = (coy - (-1.0f + (float)(2 * iwp + 1) * (1.0f / 128.0f))) * 128.0f;

        // ---- 2x2 gather (8 B each; column pair usually one cache line) ----
        const uint2* rm = Sp + ihm * 128;
        const uint2* rp = Sp + ihp * 128;
        uint2 v00 = rm[iwm], v01 = rm[iwp];
        uint2 v10 = rp[iwm], v11 = rp[iwp];

        float s[4][3];
        {
            float2 p;
            p = __half22float2(*reinterpret_cast<const __half2*>(&v00.x));
            s[0][0] = p.x; s[0][1] = p.y;
            s[0][2] = __half2float(__ushort_as_half((unsigned short)(v00.y & 0xffffu)));
            p = __half22float2(*reinterpret_cast<const __half2*>(&v01.x));
            s[1][0] = p.x; s[1][1] = p.y;
            s[1][2] = __half2float(__ushort_as_half((unsigned short)(v01.y & 0xffffu)));
            p = __half22float2(*reinterpret_cast<const __half2*>(&v10.x));
            s[2][0] = p.x; s[2][1] = p.y;
            s[2][2] = __half2float(__ushort_as_half((unsigned short)(v10.y & 0xffffu)));
            p = __half22float2(*reinterpret_cast<const __half2*>(&v11.x));
            s[3][0] = p.x; s[3][1] = p.y;
            s[3][2] = __half2float(__ushort_as_half((unsigned short)(v11.y & 0xffffu)));
        }

        float rxs[4] = {relxm, relxm, relxp, relxp};
        float rys[4] = {relym, relyp, relym, relyp};

        float pr[4][3];
        float area[4];
#pragma unroll
        for (int sdx = 0; sdx < 4; ++sdx) {
            float relx = rxs[sdx], rely = rys[sdx];
            pr[sdx][0] = s[sdx][0] + relx * wx0 + rely * wy0 + rcx * wc0 + rcy * wd0 + b0;
            pr[sdx][1] = s[sdx][1] + relx * wx1 + rely * wy1 + rcx * wc1 + rcy * wd1 + b1;
            pr[sdx][2] = s[sdx][2] + relx * wx2 + rely * wy2 + rcx * wc2 + rcy * wd2 + b2;
            area[sdx] = fabsf(relx * rely) + 1e-9f;
        }

        float tot = area[0] + area[1] + area[2] + area[3];
        float inv = 1.0f / tot;
        // swapped-area weights: pred[i] * area[3-i]/tot
        float g0 = area[3] * inv, g1 = area[2] * inv, g2 = area[1] * inv, g3 = area[0] * inv;

        res[k * 3 + 0] = pr[0][0] * g0 + pr[1][0] * g1 + pr[2][0] * g2 + pr[3][0] * g3;
        res[k * 3 + 1] = pr[0][1] * g0 + pr[1][1] * g1 + pr[2][1] * g2 + pr[3][1] * g3;
        res[k * 3 + 2] = pr[0][2] * g0 + pr[1][2] * g1 + pr[2][2] * g2 + pr[3][2] * g3;
    }

    float2* op = reinterpret_cast<float2*>(out + q0 * 3);  // 8B-aligned
    op[0] = make_float2(res[0], res[1]);
    op[1] = make_float2(res[2], res[3]);
    op[2] = make_float2(res[4], res[5]);
}

extern "C" void kernel_launch(void* const* d_in, const int* in_sizes, int n_in,
                              void* d_out, int out_size, void* d_ws, size_t ws_size,
                              hipStream_t stream) {
    const float* feat  = (const float*)d_in[0];  // (1,64,128,128)
    const float* coord = (const float*)d_in[1];  // (1,Q,2)
    const float* cell  = (const float*)d_in[2];  // (1,Q,2)
    const float* wgt   = (const float*)d_in[3];  // (580,3)
    const float* bias  = (const float*)d_in[4];  // (3,)
    float* out = (float*)d_out;                  // (1,Q,3) fp32
    uint2* Sp  = (uint2*)d_ws;                   // packed fp16 table, 128 KB
    unsigned* flags = (unsigned*)((char*)d_ws + 128 * 1024);  // 512 x 4 B

    liif_fused<<<NBLK, 256, 0, stream>>>(feat, coord, cell, wgt, bias, Sp, flags, out);
}

// Round 12
// 15.923 us; speedup vs baseline: 8.5009x; 8.5009x over previous
//
#include <hip/hip_runtime.h>
#include <hip/hip_fp16.h>

constexpr int Hc = 128, Wc = 128, Cc = 64;
constexpr int Qc = 512 * 512;

constexpr int PIX_PER_BLK = 16;   // conv: pixels per block (1024 blocks)
constexpr int CGRP = 16;          // conv: channel groups per block
constexpr int CPER = Cc / CGRP;   // 4 channels per group

// ---------------------------------------------------------------------------
// Kernel 1: 3x3 conv (64 -> 3 ch) folded from unfold3+matmul, over 128x128.
// 1024 blocks; tid = cg*16 + px; LDS tree-reduce over 16 channel groups.
// Interior blocks (756/1024: no image-border pixel) take an unguarded
// fast path -- no bounds compare/select per load.
// Output: packed fp16 {s0,s1,s2,pad} = 8 B/pixel -> 128 KB table.
// ---------------------------------------------------------------------------
__global__ __launch_bounds__(256) void conv3x3_S(const float* __restrict__ feat,
                                                 const float* __restrict__ wgt,
                                                 uint2* __restrict__ Sp) {
    __shared__ float ws[576 * 3];
    for (int i = threadIdx.x; i < 576 * 3; i += 256) ws[i] = wgt[i];

    __shared__ float part[CGRP][PIX_PER_BLK][3];   // [16][16][3]

    int px = threadIdx.x & (PIX_PER_BLK - 1);
    int cg = threadIdx.x >> 4;        // 0..15
    int pix = blockIdx.x * PIX_PER_BLK + px;
    int y = pix >> 7;                 // uniform per block (16-px strip in one row)
    int x = pix & 127;

    // block-uniform interior test: strip start x0, row y
    int x0 = (blockIdx.x * PIX_PER_BLK) & 127;
    bool interior = (y > 0) && (y < Hc - 1) && (x0 != 0) && (x0 + PIX_PER_BLK != Wc);

    __syncthreads();                  // ws ready

    float a0 = 0.f, a1 = 0.f, a2 = 0.f;
    const int c0 = cg * CPER;

    if (interior) {
        // unguarded: all 9 neighbors in-bounds for every pixel of the strip
        const float* base = feat + c0 * (Hc * Wc) + (y - 1) * Wc + (x - 1);
#pragma unroll
        for (int ci = 0; ci < CPER; ++ci) {
            const float* fc = base + ci * (Hc * Wc);
            const float* wr = ws + (c0 + ci) * 27;
#pragma unroll
            for (int di = 0; di < 3; ++di) {
#pragma unroll
                for (int dj = 0; dj < 3; ++dj) {
                    float v = fc[di * Wc + dj];
                    const float* wk = wr + (di * 3 + dj) * 3;
                    a0 = fmaf(v, wk[0], a0);
                    a1 = fmaf(v, wk[1], a1);
                    a2 = fmaf(v, wk[2], a2);
                }
            }
        }
    } else {
#pragma unroll
        for (int ci = 0; ci < CPER; ++ci) {
            int c = c0 + ci;
            const float* fc = feat + c * Hc * Wc;
            const float* wr = ws + c * 27;
#pragma unroll
            for (int di = 0; di < 3; ++di) {
                int yy = y + di - 1;
                bool yok = (unsigned)yy < (unsigned)Hc;
#pragma unroll
                for (int dj = 0; dj < 3; ++dj) {
                    int xx = x + dj - 1;
                    bool ok = yok && ((unsigned)xx < (unsigned)Wc);
                    float v = ok ? fc[yy * Wc + xx] : 0.f;
                    const float* wk = wr + (di * 3 + dj) * 3;
                    a0 = fmaf(v, wk[0], a0);
                    a1 = fmaf(v, wk[1], a1);
                    a2 = fmaf(v, wk[2], a2);
                }
            }
        }
    }

    part[cg][px][0] = a0;
    part[cg][px][1] = a1;
    part[cg][px][2] = a2;
    __syncthreads();

    // tree reduce over channel groups: 16 -> 8 -> 4 -> 2 -> 1
#pragma unroll
    for (int step = CGRP / 2; step > 0; step >>= 1) {
        if (cg < step) {
            part[cg][px][0] += part[cg + step][px][0];
            part[cg][px][1] += part[cg + step][px][1];
            part[cg][px][2] += part[cg + step][px][2];
        }
        __syncthreads();
    }

    if (cg == 0) {
        unsigned short u0 = __half_as_ushort(__float2half_rn(part[0][px][0]));
        unsigned short u1 = __half_as_ushort(__float2half_rn(part[0][px][1]));
        unsigned short u2 = __half_as_ushort(__float2half_rn(part[0][px][2]));
        uint2 o;
        o.x = (unsigned)u0 | ((unsigned)u1 << 16);
        o.y = (unsigned)u2;
        Sp[pix] = o;                                // 16 lanes, 128B coalesced
    }
}

static __device__ __forceinline__ void unpack3(uint2 v, float& s0, float& s1, float& s2) {
    float2 p = __half22float2(*reinterpret_cast<const __half2*>(&v.x));
    s0 = p.x;
    s1 = p.y;
    s2 = __half2float(__ushort_as_half((unsigned short)(v.y & 0xffffu)));
}

// ---------------------------------------------------------------------------
// Kernel 2: 2 queries/thread, global-memory gathers (L2-hot 128 KB table).
// The 4 shifts are the cross product {ih_m,ih_p} x {iw_m,iw_p}: per-axis
// index/rel algebra, 2x2 8B gathers (column pairs share a cache line),
// linear tail + swapped-area blend.
// ---------------------------------------------------------------------------
__global__ __launch_bounds__(256) void liif_query(const float* __restrict__ coord,
                                                  const float* __restrict__ cell,
                                                  const float* __restrict__ wgt,
                                                  const float* __restrict__ bias,
                                                  const uint2* __restrict__ Sp,
                                                  float* __restrict__ out) {
    int t = blockIdx.x * 256 + threadIdx.x;     // grid sized exactly Q/2
    int q0 = t * 2;

    float4 co = *reinterpret_cast<const float4*>(coord + q0 * 2);  // x0,y0,x1,y1
    float4 ce = *reinterpret_cast<const float4*>(cell + q0 * 2);

    // tail weight rows 576..579 and bias (uniform, scalar-cached)
    float wx0 = wgt[576 * 3 + 0], wx1 = wgt[576 * 3 + 1], wx2 = wgt[576 * 3 + 2];
    float wy0 = wgt[577 * 3 + 0], wy1 = wgt[577 * 3 + 1], wy2 = wgt[577 * 3 + 2];
    float wc0 = wgt[578 * 3 + 0], wc1 = wgt[578 * 3 + 1], wc2 = wgt[578 * 3 + 2];
    float wd0 = wgt[579 * 3 + 0], wd1 = wgt[579 * 3 + 1], wd2 = wgt[579 * 3 + 2];
    float b0 = bias[0], b1 = bias[1], b2 = bias[2];

    // double-computed constants cast to fp32 (match numpy float64 scalar math)
    constexpr float SHN = (float)(-1.0 / 128.0 + 1e-6);
    constexpr float SHP = (float)( 1.0 / 128.0 + 1e-6);
    constexpr float CLO = (float)(-1.0 + 1e-6);
    constexpr float CHI = (float)( 1.0 - 1e-6);

    float res[6];
#pragma unroll
    for (int k = 0; k < 2; ++k) {
        float cox = k ? co.z : co.x;
        float coy = k ? co.w : co.y;
        float rcx = (k ? ce.z : ce.x) * 128.0f;
        float rcy = (k ? ce.w : ce.y) * 128.0f;

        // ---- per-axis index + rel algebra (shifts are exactly +-0.5 px) ----
        // After the clip to [CLO,CHI], (c+1)*64 is in [1.2e-7, 127.99994],
        // so floor already lands in [0,127] -- int clamps are redundant
        // (the reference's post-floor clip is a no-op for the same reason).
        float cxm = fminf(fmaxf(cox + SHN, CLO), CHI);
        float cxp = fminf(fmaxf(cox + SHP, CLO), CHI);
        int ihm = (int)floorf((cxm + 1.0f) * 64.0f);
        int ihp = (int)floorf((cxp + 1.0f) * 64.0f);
        float relxm = (cox - (-1.0f + (float)(2 * ihm + 1) * (1.0f / 128.0f))) * 128.0f;
        float relxp = (cox - (-1.0f + (float)(2 * ihp + 1) * (1.0f / 128.0f))) * 128.0f;

        float cym = fminf(fmaxf(coy + SHN, CLO), CHI);
        float cyp = fminf(fmaxf(coy + SHP, CLO), CHI);
        int iwm = (int)floorf((cym + 1.0f) * 64.0f);
        int iwp = (int)floorf((cyp + 1.0f) * 64.0f);
        float relym = (coy - (-1.0f + (float)(2 * iwm + 1) * (1.0f / 128.0f))) * 128.0f;
        float relyp = (coy - (-1.0f + (float)(2 * iwp + 1) * (1.0f / 128.0f))) * 128.0f;

        // ---- 2x2 gather (8 B each; column pair usually one cache line) ----
        const uint2* rm = Sp + ihm * 128;
        const uint2* rp = Sp + ihp * 128;
        uint2 v00 = rm[iwm], v01 = rm[iwp];
        uint2 v10 = rp[iwm], v11 = rp[iwp];

        float s[4][3];
        unpack3(v00, s[0][0], s[0][1], s[0][2]);   // (-1,-1)
        unpack3(v01, s[1][0], s[1][1], s[1][2]);   // (-1,+1)
        unpack3(v10, s[2][0], s[2][1], s[2][2]);   // (+1,-1)
        unpack3(v11, s[3][0], s[3][1], s[3][2]);   // (+1,+1)

        float rxs[4] = {relxm, relxm, relxp, relxp};
        float rys[4] = {relym, relyp, relym, relyp};

        float pr[4][3];
        float area[4];
#pragma unroll
        for (int sdx = 0; sdx < 4; ++sdx) {
            float relx = rxs[sdx], rely = rys[sdx];
            pr[sdx][0] = s[sdx][0] + relx * wx0 + rely * wy0 + rcx * wc0 + rcy * wd0 + b0;
            pr[sdx][1] = s[sdx][1] + relx * wx1 + rely * wy1 + rcx * wc1 + rcy * wd1 + b1;
            pr[sdx][2] = s[sdx][2] + relx * wx2 + rely * wy2 + rcx * wc2 + rcy * wd2 + b2;
            area[sdx] = fabsf(relx * rely) + 1e-9f;
        }

        float tot = area[0] + area[1] + area[2] + area[3];
        float inv = 1.0f / tot;
        // swapped-area weights: pred[i] * area[3-i]/tot
        float g0 = area[3] * inv, g1 = area[2] * inv, g2 = area[1] * inv, g3 = area[0] * inv;

        res[k * 3 + 0] = pr[0][0] * g0 + pr[1][0] * g1 + pr[2][0] * g2 + pr[3][0] * g3;
        res[k * 3 + 1] = pr[0][1] * g0 + pr[1][1] * g1 + pr[2][1] * g2 + pr[3][1] * g3;
        res[k * 3 + 2] = pr[0][2] * g0 + pr[1][2] * g1 + pr[2][2] * g2 + pr[3][2] * g3;
    }

    float2* op = reinterpret_cast<float2*>(out + q0 * 3);  // 8B-aligned (24B/thread)
    op[0] = make_float2(res[0], res[1]);
    op[1] = make_float2(res[2], res[3]);
    op[2] = make_float2(res[4], res[5]);
}

extern "C" void kernel_launch(void* const* d_in, const int* in_sizes, int n_in,
                              void* d_out, int out_size, void* d_ws, size_t ws_size,
                              hipStream_t stream) {
    const float* feat  = (const float*)d_in[0];  // (1,64,128,128)
    const float* coord = (const float*)d_in[1];  // (1,Q,2)
    const float* cell  = (const float*)d_in[2];  // (1,Q,2)
    const float* wgt   = (const float*)d_in[3];  // (580,3)
    const float* bias  = (const float*)d_in[4];  // (3,)
    float* out = (float*)d_out;                  // (1,Q,3) fp32
    uint2* Sp  = (uint2*)d_ws;                   // packed fp16 table, 128 KB

    conv3x3_S<<<(Hc * Wc) / PIX_PER_BLK, 256, 0, stream>>>(feat, wgt, Sp);
    liif_query<<<Qc / 512, 256, 0, stream>>>(coord, cell, wgt, bias, Sp, out);
}